// Round 15
// baseline (1361.496 us; speedup 1.0000x reference)
//
#include <hip/hip_runtime.h>
#include <hip/hip_bf16.h>

// SwiGLU FFN, fp32 in/out: out = clamp(silu(x@w1t) * (x@w3t), ±65504) @ w2t
// x[8192,3072], w13[16384,3072] (rows 0..8191 = w3 -> x3, 8192.. = w1 -> x1), w2[3072,8192].
// Round-15: gate/up as TWO literal clones of the proven down11 skeleton (67% MfmaUtil):
//   k_gemm3: g = x@w3t (plain bf16 store), k_gemm1: h1 = x@w1t with epilogue
//   g[idx] = clamp(silu(h1)*g[idx]) — per-element single-owner in-place RMW (race-free).
//   Then proven k_down11. No new sync structures; every GEMM is the same skeleton:
//   256x128 tile, BK=64, 3-buf depth-2, VMCNT(6), 1 barrier/K-tile, 16x16x32 frags,
//   row&7 slot swizzle (0 conflicts), rule #21 both-sides swizzle.

typedef __attribute__((ext_vector_type(8))) __bf16 bf16x8;
typedef __attribute__((ext_vector_type(4))) float f32x4;

#define GLD_LDS16(gptr, lptr)                                                        \
  __builtin_amdgcn_global_load_lds(                                                  \
      (const __attribute__((address_space(1))) void*)(gptr),                         \
      (__attribute__((address_space(3))) void*)(lptr), 16, 0, 0)

#define VMCNT(n) asm volatile("s_waitcnt vmcnt(" #n ")" ::: "memory")
#define BAR()    __builtin_amdgcn_s_barrier()

#define MFMA16(a, b, c) __builtin_amdgcn_mfma_f32_16x16x32_bf16((a), (b), (c), 0, 0, 0)

__device__ __forceinline__ __bf16 bfr(float f) {  // RNE fp32->bf16
  unsigned int u = __builtin_bit_cast(unsigned int, f);
  unsigned short r = (unsigned short)((u + 0x7FFFu + ((u >> 16) & 1u)) >> 16);
  return __builtin_bit_cast(__bf16, r);
}

// ---------------- fp32 -> bf16 conversion pre-pass ----------------
__global__ __launch_bounds__(256)
void k_cvt(const float* __restrict__ src, unsigned short* __restrict__ dst, long n) {
  long i = ((long)blockIdx.x * 256 + threadIdx.x) * 8;
  const long stride = (long)gridDim.x * 256 * 8;
  for (; i < n; i += stride) {
    float4 f0 = *(const float4*)(src + i);
    float4 f1 = *(const float4*)(src + i + 4);
    bf16x8 o;
    o[0] = bfr(f0.x); o[1] = bfr(f0.y); o[2] = bfr(f0.z); o[3] = bfr(f0.w);
    o[4] = bfr(f1.x); o[5] = bfr(f1.y); o[6] = bfr(f1.z); o[7] = bfr(f1.w);
    *(bf16x8*)(dst + i) = o;
  }
}

// ============ shared GEMM body: C-tile 256x128, BK=64, down11 skeleton ============
// 8 waves (4M x 2N), per-wave 64x64. Per K-tile: VMCNT(6); BAR; 16 ds_read;
// stage c+2 into buffer of c-1; prio1; 32 MFMA; prio0.
// EPI: 0 = plain bf16 store to G; 1 = swiglu RMW on G; 2 = fp32 store to Out.
template <int KDIM, int EPI>
__global__ __launch_bounds__(512, 2)
void k_gemm(const unsigned short* __restrict__ A,
            const unsigned short* __restrict__ B,
            __hip_bfloat16* __restrict__ G,
            float* __restrict__ Out,
            const int nNb, const int ldc)
{
  constexpr int K = KDIM, NT = K / 64;
  __shared__ unsigned short lds[73728];  // 144KB: A[3]@0 (16384 ea) | B[3]@49152 (8192 ea)

  const int t = threadIdx.x, l = t & 63, wid = t >> 6;
  const int wm = wid >> 1, wn = wid & 1;          // 4M x 2N
  const int l15 = l & 15, lhi = l >> 4, sw = l15 & 7;

  const int bid = blockIdx.x;                     // grid = 8 * chunk, XCD-chunked
  const int chunk = (gridDim.x >> 3);
  const int swz = (bid & 7) * chunk + (bid >> 3);
  const int mb = swz / nNb, nb = swz % nNb;

  const int srow = t >> 3;
  const int scol = ((t & 7) ^ (srow & 7)) * 8;
  const unsigned short* ga = A + (size_t)(mb * 256 + srow) * K + scol;
  const unsigned short* wb = B + (size_t)(nb * 128 + srow) * K + scol;
  const int lo = t * 8;

#define DST_A(e, kt) do {                                                       \
    GLD_LDS16(ga + (kt),                 lds + (e) * 16384 + lo);               \
    GLD_LDS16(ga + (size_t)64 * K + (kt),  lds + (e) * 16384 + 4096 + lo);      \
    GLD_LDS16(ga + (size_t)128 * K + (kt), lds + (e) * 16384 + 8192 + lo);      \
    GLD_LDS16(ga + (size_t)192 * K + (kt), lds + (e) * 16384 + 12288 + lo);     \
  } while (0)
#define DST_B(e, kt) do {                                                       \
    GLD_LDS16(wb + (kt),                lds + 49152 + (e) * 8192 + lo);         \
    GLD_LDS16(wb + (size_t)64 * K + (kt), lds + 49152 + (e) * 8192 + 4096 + lo); \
  } while (0)

  f32x4 acc[4][4];
#pragma unroll
  for (int mf = 0; mf < 4; ++mf)
#pragma unroll
    for (int nf = 0; nf < 4; ++nf)
      acc[mf][nf] = (f32x4){0.f, 0.f, 0.f, 0.f};

  // prologue: tiles 0,1 (6 loads each)
  DST_B(0, 0);  DST_A(0, 0);
  DST_B(1, 64); DST_A(1, 64);

  for (int c = 0; c < NT; ++c) {
    const int e = c % 3;
    const int eS = (c + 2) % 3;
    const int k2 = (c + 2 < NT ? c + 2 : 0) * 64;

    VMCNT(6);    // tile c's 6 landed (tile c+1's 6 in flight)
    BAR();

    bf16x8 ra[4][2], rb[4][2];
#pragma unroll
    for (int mf = 0; mf < 4; ++mf)
#pragma unroll
      for (int kk = 0; kk < 2; ++kk)
        ra[mf][kk] = *(const bf16x8*)(lds + e * 16384 + (wm * 64 + mf * 16 + l15) * 64 + ((kk * 4 + lhi) ^ sw) * 8);
#pragma unroll
    for (int nf = 0; nf < 4; ++nf)
#pragma unroll
      for (int kk = 0; kk < 2; ++kk)
        rb[nf][kk] = *(const bf16x8*)(lds + 49152 + e * 8192 + (wn * 64 + nf * 16 + l15) * 64 + ((kk * 4 + lhi) ^ sw) * 8);

    // stage tile c+2 into buffer of tile c-1 (reads done before this iter's barrier)
    DST_B(eS, k2);
    DST_A(eS, k2);

    __builtin_amdgcn_s_setprio(1);
#pragma unroll
    for (int mf = 0; mf < 4; ++mf)
#pragma unroll
      for (int nf = 0; nf < 4; ++nf)
#pragma unroll
        for (int kk = 0; kk < 2; ++kk)
          acc[mf][nf] = MFMA16(ra[mf][kk], rb[nf][kk], acc[mf][nf]);
    __builtin_amdgcn_s_setprio(0);
  }

  const int r0 = mb * 256 + wm * 64;
  const int c0 = nb * 128 + wn * 64;
#pragma unroll
  for (int mf = 0; mf < 4; ++mf)
#pragma unroll
    for (int nf = 0; nf < 4; ++nf)
#pragma unroll
      for (int r = 0; r < 4; ++r) {
        const size_t idx = (size_t)(r0 + mf * 16 + lhi * 4 + r) * ldc + (c0 + nf * 16 + l15);
        if constexpr (EPI == 0) {
          G[idx] = __float2bfloat16(acc[mf][nf][r]);
        } else if constexpr (EPI == 1) {
          // swiglu RMW: this thread is the sole owner of G[idx]
          float h3 = __bfloat162float(G[idx]);      // x3 (from k_gemm3)
          float h1 = acc[mf][nf][r];                // x1 (this GEMM)
          float s  = h1 / (1.f + __expf(-h1));
          float g  = fminf(fmaxf(s * h3, -65504.f), 65504.f);
          G[idx] = __float2bfloat16(g);
        } else {
          Out[idx] = acc[mf][nf][r];
        }
      }
#undef DST_A
#undef DST_B
}

extern "C" void kernel_launch(void* const* d_in, const int* in_sizes, int n_in,
                              void* d_out, int out_size, void* d_ws, size_t ws_size,
                              hipStream_t stream) {
  const float* x   = (const float*)d_in[0];   // [2,4096,3072] f32
  const float* w13 = (const float*)d_in[1];   // [16384,3072] f32
  const float* w2  = (const float*)d_in[2];   // [3072,8192] f32
  float* out = (float*)d_out;                 // [2,4096,3072] f32

  const long NX = 25165824L, NW13 = 50331648L, NW2 = 25165824L;
  const size_t XB = 50331648, W13B = 100663296, W2B = 50331648;

  unsigned short* xb   = (unsigned short*)d_ws;
  unsigned short* w13b = (unsigned short*)((char*)d_ws + XB);
  unsigned short* w2b  = (unsigned short*)((char*)d_ws + XB + W13B);
  __hip_bfloat16* g    = (__hip_bfloat16*)((char*)d_ws + XB + W13B + W2B);

  k_cvt<<<2048, 256, 0, stream>>>(x,   xb,   NX);
  k_cvt<<<2048, 256, 0, stream>>>(w13, w13b, NW13);
  k_cvt<<<2048, 256, 0, stream>>>(w2,  w2b,  NW2);

  // g = x @ w3t  (w13 rows 0..8191), plain bf16 store.  32x64 tiles = 2048 blocks.
  k_gemm<3072, 0><<<2048, 512, 0, stream>>>(xb, w13b, g, nullptr, 64, 8192);
  // h1 = x @ w1t (w13 rows 8192..), epilogue: g[idx] = clamp(silu(h1)*g[idx]).
  k_gemm<3072, 1><<<2048, 512, 0, stream>>>(xb, w13b + (size_t)8192 * 3072, g,
                                            nullptr, 64, 8192);
  // out = g @ w2t.  32x24 tiles = 768 blocks.
  k_gemm<8192, 2><<<768, 512, 0, stream>>>((const unsigned short*)g, w2b, nullptr,
                                           out, 24, 3072);
}